// Round 5
// baseline (2675.373 us; speedup 1.0000x reference)
//
#include <hip/hip_runtime.h>
#include <math.h>

constexpr int NB = 32;      // batches
constexpr int NP = 1024;    // points per batch
constexpr int NK = 10;      // k nearest (includes self)
constexpr int BN = NB * NP;
constexpr int NBCH = 8;     // batches per dist chunk
constexpr int NSLOT = 1024; // partial-reduction slots for PairNorm stats

__device__ __forceinline__ float4 ld4(const float* p){ return *reinterpret_cast<const float4*>(p); }
__device__ __forceinline__ float2 ld2(const float* p){ return *reinterpret_cast<const float2*>(p); }
__device__ __forceinline__ void st4(float* p, float4 v){ *reinterpret_cast<float4*>(p) = v; }

// ---------------- sq norms of pos ----------------
__global__ __launch_bounds__(256) void k_sq_pos(const float* __restrict__ x, float* __restrict__ sq){
  int i = blockIdx.x*256 + threadIdx.x;
  float2 v = ld2(x + (size_t)2*i);
  sq[i] = v.x*v.x + v.y*v.y;
}

// ---------------- dist matrix, DIN=2 (layer 1) ----------------
__global__ __launch_bounds__(256) void k_dist2(const float* __restrict__ x,
    const float* __restrict__ sq, float* __restrict__ dist, int b0){
  int bz = blockIdx.z;
  int b = b0 + bz;
  int n0 = blockIdx.x*128, m0 = blockIdx.y*128;
  int ry = threadIdx.x>>4, rx = threadIdx.x&15;
  const float* xb = x + (size_t)b*NP*2;
  const float* sqb = sq + (size_t)b*NP;
  float2 av[8], bv[8]; float sn[8], sm[8];
#pragma unroll
  for (int k=0;k<8;++k){
    av[k] = ld2(xb + (size_t)(n0+ry*8+k)*2);
    bv[k] = ld2(xb + (size_t)(m0+rx*8+k)*2);
    sn[k] = sqb[n0+ry*8+k];
    sm[k] = sqb[m0+rx*8+k];
  }
  float* dbase = dist + ((size_t)bz*NP + n0 + ry*8)*NP + m0 + rx*8;
#pragma unroll
  for (int k=0;k<8;++k){
    float r[8];
#pragma unroll
    for (int l=0;l<8;++l){
      float dot = av[k].x*bv[l].x + av[k].y*bv[l].y;
      r[l] = (sn[k] + sm[l]) - 2.f*dot;
    }
    st4(dbase + (size_t)k*NP,     make_float4(r[0],r[1],r[2],r[3]));
    st4(dbase + (size_t)k*NP + 4, make_float4(r[4],r[5],r[6],r[7]));
  }
}

// ---------------- pre-transpose W into WT[n][k] (n in [0,2*DOUT)) ----------------
template<int DIN, int DOUT>
__global__ void k_wt(const float* __restrict__ W, float* __restrict__ WT){
  int n = blockIdx.x, k = threadIdx.x;
  float v = (n < DOUT) ? W[(size_t)k*DOUT + n]
                       : W[(size_t)DIN*DOUT + (size_t)k*DOUT + (n - DOUT)];
  WT[(size_t)n*DIN + k] = v;
}

// ---------------- unified 128x128 tile kernel (dist + gemm) ----------------
// BK=32 chunks, single 32KB LDS buffer, register-prefetch double buffering:
//   barrier -> issue loads(ch+1) -> compute(ch) -> barrier -> ds_write(ch+1)
// LDS layout: slot s holds (row r=s>>3, col c=((s&7)-(r>>3))&7) of the chunk
// => read (row, d4) at slot row*8 + ((d4 + (row>>3))&7)  (rotation swizzle).
template<int DIN, bool DIST>
__global__ __launch_bounds__(256) void k_tile(const float* __restrict__ xa,
    const float* __restrict__ bsrc, const float* __restrict__ sq,
    float* __restrict__ out, int aux0, int outLD){
  constexpr int C = DIN/32;
  __shared__ float4 as4[1024];
  __shared__ float4 bs4[1024];
  int tid = threadIdx.x;
  const float* Arow; const float* Brow;
  float* obase; const float* sqn = nullptr; const float* sqm = nullptr;
  if constexpr (DIST){
    int bz = blockIdx.z; int b = aux0 + bz;
    int n0 = blockIdx.x*128, m0 = blockIdx.y*128;
    const float* xb = xa + (size_t)b*NP*DIN;
    Arow = xb + (size_t)n0*DIN;
    Brow = xb + (size_t)m0*DIN;
    sqn = sq + (size_t)b*NP + n0;
    sqm = sq + (size_t)b*NP + m0;
    obase = out + ((size_t)bz*NP + n0)*NP + m0;
  } else {
    int n0 = blockIdx.x*128, m0 = blockIdx.y*128;
    Arow = xa + (size_t)(aux0 + n0)*DIN;
    Brow = bsrc + (size_t)m0*DIN;
    obase = out + (size_t)n0*outLD + m0;
  }
  // per-thread staging source offsets (chunk-invariant part)
  const float* pA[4]; const float* pB[4];
#pragma unroll
  for (int i=0;i<4;++i){
    int s = tid + 256*i;
    int r = s>>3;
    int c = ((s&7) - (r>>3)) & 7;
    pA[i] = Arow + (size_t)r*DIN + 4*c;
    pB[i] = Brow + (size_t)r*DIN + 4*c;
  }
  float4 sa[4], sb[4];
#pragma unroll
  for (int i=0;i<4;++i){ sa[i] = ld4(pA[i]); sb[i] = ld4(pB[i]); }
#pragma unroll
  for (int i=0;i<4;++i){ as4[tid+256*i] = sa[i]; bs4[tid+256*i] = sb[i]; }

  int ry = tid>>4, rx = tid&15;
  float acc[8][8];
#pragma unroll
  for (int k=0;k<8;++k)
#pragma unroll
    for (int l=0;l<8;++l) acc[k][l] = 0.f;

  for (int ch=0; ch<C; ++ch){
    __syncthreads();                       // staged data visible
    if (ch+1 < C){
#pragma unroll
      for (int i=0;i<4;++i){ sa[i] = ld4(pA[i] + (ch+1)*32); sb[i] = ld4(pB[i] + (ch+1)*32); }
    }
#pragma unroll
    for (int d4=0; d4<8; ++d4){
      float4 a_[8], b_[8];
#pragma unroll
      for (int k=0;k<8;++k) a_[k] = as4[(ry*8+k)*8 + ((d4 + ry)&7)];
#pragma unroll
      for (int l=0;l<8;++l) b_[l] = bs4[(rx*8+l)*8 + ((d4 + rx)&7)];
#pragma unroll
      for (int k=0;k<8;++k)
#pragma unroll
        for (int l=0;l<8;++l)
          acc[k][l] += a_[k].x*b_[l].x + a_[k].y*b_[l].y + a_[k].z*b_[l].z + a_[k].w*b_[l].w;
    }
    __syncthreads();                       // all reads of this chunk done
    if (ch+1 < C){
#pragma unroll
      for (int i=0;i<4;++i){ as4[tid+256*i] = sa[i]; bs4[tid+256*i] = sb[i]; }
    }
  }

  if constexpr (DIST){
    float sn[8], sm[8];
#pragma unroll
    for (int k=0;k<8;++k){ sn[k] = sqn[ry*8+k]; sm[k] = sqm[rx*8+k]; }
#pragma unroll
    for (int k=0;k<8;++k){
      float r[8];
#pragma unroll
      for (int l=0;l<8;++l) r[l] = (sn[k]+sm[l]) - 2.f*acc[k][l];
      float* op = obase + (size_t)(ry*8+k)*NP + rx*8;
      st4(op,     make_float4(r[0],r[1],r[2],r[3]));
      st4(op + 4, make_float4(r[4],r[5],r[6],r[7]));
    }
  } else {
#pragma unroll
    for (int k=0;k<8;++k){
      float* op = obase + (size_t)(ry*8+k)*outLD + rx*8;
      st4(op,     make_float4(acc[k][0],acc[k][1],acc[k][2],acc[k][3]));
      st4(op + 4, make_float4(acc[k][4],acc[k][5],acc[k][6],acc[k][7]));
    }
  }
}

// ---------------- gather-max epilogue: h = relu(z + b - y_self + max_j y_j) ----------------
template<int DOUT>
__global__ __launch_bounds__(256) void k_gmax(const float* __restrict__ xcat,
    const int* __restrict__ idx, const float* __restrict__ bias,
    float* __restrict__ hout, float* __restrict__ spart, int p_base, int slot_base){
  constexpr int TP = DOUT/4;        // threads per point
  constexpr int ROWS = 256/TP;      // points in flight
  constexpr int PPT = 32/ROWS;      // points per thread
  __shared__ int idx_s[32*NK];
  __shared__ float red[1024];       // ROWS*DOUT == 1024 floats
  __shared__ float ssp[4];
  int c4 = threadIdx.x % TP, pr = threadIdx.x / TP;
  int c = 4*c4;
  int p0 = blockIdx.x*32 + p_base;          // global first point of block
  for (int t=threadIdx.x; t<32*NK; t+=256) idx_s[t] = idx[(size_t)p0*NK + t];
  __syncthreads();
  float4 b4 = ld4(bias + c);
  float4 fsum = make_float4(0.f,0.f,0.f,0.f);
  float ss = 0.f;
  int pbl = (((p0 - p_base) >> 10) << 10);  // local batch base row
#pragma unroll
  for (int t=0; t<PPT; ++t){
    int pl = pr + t*ROWS;
    int lrow = (p0 - p_base) + pl;
    const float* row = xcat + (size_t)lrow*(2*DOUT);
    float4 z = ld4(row + c), ys = ld4(row + DOUT + c);
    float4 mv = make_float4(-__builtin_inff(),-__builtin_inff(),-__builtin_inff(),-__builtin_inff());
    for (int j=0;j<NK;++j){
      int q = pbl + idx_s[pl*NK + j];
      float4 g = ld4(xcat + (size_t)q*(2*DOUT) + DOUT + c);
      mv.x = fmaxf(mv.x, g.x); mv.y = fmaxf(mv.y, g.y);
      mv.z = fmaxf(mv.z, g.z); mv.w = fmaxf(mv.w, g.w);
    }
    float4 v;
    v.x = fmaxf(z.x + b4.x - ys.x + mv.x, 0.f);
    v.y = fmaxf(z.y + b4.y - ys.y + mv.y, 0.f);
    v.z = fmaxf(z.z + b4.z - ys.z + mv.z, 0.f);
    v.w = fmaxf(z.w + b4.w - ys.w + mv.w, 0.f);
    st4(hout + (size_t)(p0 + pl)*DOUT + c, v);
    fsum.x += v.x; fsum.y += v.y; fsum.z += v.z; fsum.w += v.w;
    ss += v.x*v.x + v.y*v.y + v.z*v.z + v.w*v.w;
  }
  st4(&red[pr*DOUT + c], fsum);
#pragma unroll
  for (int off=32; off; off>>=1) ss += __shfl_xor(ss, off, 64);
  if ((threadIdx.x&63)==0) ssp[threadIdx.x>>6] = ss;
  __syncthreads();
  int slot = slot_base + blockIdx.x;
  for (int o=threadIdx.x; o<DOUT; o+=256){
    float s = 0.f;
#pragma unroll
    for (int r=0;r<ROWS;++r) s += red[r*DOUT + o];
    spart[(size_t)o*NSLOT + slot] = s;
  }
  if (threadIdx.x==0) spart[(size_t)DOUT*NSLOT + slot] = ssp[0]+ssp[1]+ssp[2]+ssp[3];
}

// ---------------- top-k selection (wave per row) ----------------
__global__ __launch_bounds__(256) void k_topk(const float* __restrict__ dist,
    int* __restrict__ idx, int b0){
  int wave = threadIdx.x>>6, lane = threadIdx.x&63;
  int rowg = blockIdx.x*4 + wave;          // = bz*NP + n
  int bz = rowg >> 10, n = rowg & 1023;
  const float* dr = dist + (size_t)rowg * NP;
  float dv[16];
#pragma unroll
  for (int t=0;t<16;++t) dv[t] = dr[lane + 64*t];
  int* out = idx + ((size_t)(b0+bz)*NP + n)*NK;
  for (int kk=0; kk<NK; ++kk){
    float bvv = dv[0]; int bm = lane;
#pragma unroll
    for (int t=1;t<16;++t){
      int m = lane + 64*t;
      if (dv[t] < bvv){ bvv = dv[t]; bm = m; }   // ascending m, strict < => lowest idx on tie
    }
#pragma unroll
    for (int off=32; off; off>>=1){
      float ov = __shfl_xor(bvv, off, 64);
      int om = __shfl_xor(bm, off, 64);
      if (ov < bvv || (ov == bvv && om < bm)){ bvv = ov; bm = om; }
    }
    if (lane == 0) out[kk] = bm;
    int tsel = bm>>6, lsel = bm&63;
#pragma unroll
    for (int t=0;t<16;++t)
      if (t == tsel && lane == lsel) dv[t] = __builtin_inff();   // static indexing
  }
}

// ---------------- edge conv layer 1 (din=2, dout=64) ----------------
__global__ __launch_bounds__(256) void k_edge1(const float* __restrict__ x,
    const int* __restrict__ idx, const float* __restrict__ W,
    const float* __restrict__ bias, float* __restrict__ hout,
    float* __restrict__ spart){
  __shared__ int idx_s[32*NK];
  __shared__ float red[4][64];
  __shared__ float ssw[4];
  int lane = threadIdx.x & 63, wv = threadIdx.x >> 6;
  int p0 = blockIdx.x * 32;
  int b = p0 >> 10;
  int pl0 = p0 & 1023;
  const float* xb = x + ((size_t)b<<10)*2;
  for (int t=threadIdx.x; t<32*NK; t+=256) idx_s[t] = idx[(size_t)p0*NK + t];
  __syncthreads();
  float w0=W[lane], w1=W[64+lane], w2=W[128+lane], w3=W[192+lane];
  float bi = bias[lane];
  float fsum = 0.f, ss = 0.f;
#pragma unroll
  for (int t=0;t<8;++t){
    int pl = wv*8 + t;
    float2 xi = ld2(xb + (size_t)(pl0+pl)*2);
    float common = xi.x*w0 + xi.y*w1 + bi;
    float mv = -__builtin_inff();
    for (int j=0;j<NK;++j){
      float2 xj = ld2(xb + (size_t)idx_s[pl*NK+j]*2);
      mv = fmaxf(mv, (xj.x-xi.x)*w2 + (xj.y-xi.y)*w3);
    }
    float v = fmaxf(common + mv, 0.f);
    hout[(size_t)(p0+pl)*64 + lane] = v;
    fsum += v; ss += v*v;
  }
  red[wv][lane] = fsum;
#pragma unroll
  for (int off=32; off; off>>=1) ss += __shfl_xor(ss, off, 64);
  if (lane==0) ssw[wv] = ss;
  __syncthreads();
  if (threadIdx.x < 64){
    float s = red[0][lane]+red[1][lane]+red[2][lane]+red[3][lane];
    spart[(size_t)lane*NSLOT + blockIdx.x] = s;
  }
  if (threadIdx.x==0) spart[(size_t)64*NSLOT + blockIdx.x] = ssw[0]+ssw[1]+ssw[2]+ssw[3];
}

// ---------------- finalize PairNorm stats from partials ----------------
template<int DOUT>
__global__ __launch_bounds__(256) void k_finalize2(const float* __restrict__ spart,
    float* __restrict__ stats){
  __shared__ float part[4];
  __shared__ float ssh;
  float musq = 0.f;
  for (int f = threadIdx.x; f <= DOUT; f += 256){
    const float* row = spart + (size_t)f*NSLOT;
    float4 a = make_float4(0.f,0.f,0.f,0.f);
    for (int s=0; s<NSLOT; s+=4){
      float4 v = ld4(row + s);
      a.x += v.x; a.y += v.y; a.z += v.z; a.w += v.w;
    }
    float s = (a.x + a.y) + (a.z + a.w);
    if (f < DOUT){
      float m = s * (1.f/BN);
      stats[320+f] = m;
      musq += m*m;
    } else {
      ssh = s;
    }
  }
#pragma unroll
  for (int off=32; off; off>>=1) musq += __shfl_xor(musq, off, 64);
  if ((threadIdx.x&63)==0) part[threadIdx.x>>6] = musq;
  __syncthreads();
  if (threadIdx.x==0){
    float mu2 = part[0]+part[1]+part[2]+part[3];
    float msn = ssh*(1.f/BN) - mu2;
    stats[576] = 1.f / sqrtf(1e-5f + msn);
  }
}

// ---------------- normalize in place + next-layer sq (wave per row) ----------------
template<int DOUT>
__global__ __launch_bounds__(256) void k_norm(float* __restrict__ h,
    const float* __restrict__ stats, float* __restrict__ sq){
  int lane = threadIdx.x&63, wv = threadIdx.x>>6;
  int row = blockIdx.x*4 + wv;
  float inv = stats[576];
  const float* mu = stats + 320;
  float* hr = h + (size_t)row*DOUT;
  float s = 0.f;
  if constexpr (DOUT == 64){
    float v = (hr[lane] - mu[lane]) * inv;
    hr[lane] = v;
    s = v*v;
  } else if constexpr (DOUT == 128){
    float2 x2 = ld2(hr + 2*lane), m2 = ld2(mu + 2*lane);
    float a = (x2.x - m2.x)*inv, b = (x2.y - m2.y)*inv;
    *reinterpret_cast<float2*>(hr + 2*lane) = make_float2(a,b);
    s = a*a + b*b;
  } else {
    float4 x4 = ld4(hr + 4*lane), m4 = ld4(mu + 4*lane);
    float4 v;
    v.x = (x4.x-m4.x)*inv; v.y = (x4.y-m4.y)*inv;
    v.z = (x4.z-m4.z)*inv; v.w = (x4.w-m4.w)*inv;
    st4(hr + 4*lane, v);
    s = v.x*v.x + v.y*v.y + v.z*v.z + v.w*v.w;
  }
#pragma unroll
  for (int off=32; off; off>>=1) s += __shfl_xor(s, off, 64);
  if (lane==0) sq[row] = s;
}

// ---------------- global max pool (partial) ----------------
__global__ __launch_bounds__(256) void k_pool1(const float* __restrict__ h, float* __restrict__ gpart){
  int b = blockIdx.x, c = blockIdx.y, o = threadIdx.x;
  const float* hp = h + ((size_t)b*NP + c*128)*256 + o;
  float m = -__builtin_inff();
  for (int n=0;n<128;++n) m = fmaxf(m, hp[(size_t)n*256]);
  gpart[((size_t)c*NB + b)*256 + o] = m;
}

// ---------------- pool finish + MLP head ----------------
__global__ __launch_bounds__(256) void k_head(const float* __restrict__ gpart,
    const float* __restrict__ Wl1, const float* __restrict__ bl1,
    const float* __restrict__ Wl2, const float* __restrict__ bl2,
    float* __restrict__ out){
  __shared__ float g_s[256];
  __shared__ float h_s[64];
  int b = blockIdx.x, t = threadIdx.x;
  float m = -__builtin_inff();
  for (int c=0;c<8;++c) m = fmaxf(m, gpart[((size_t)c*NB + b)*256 + t]);
  g_s[t] = m;
  __syncthreads();
  if (t < 64){
    float a = bl1[t];
    for (int k=0;k<256;++k) a += g_s[k]*Wl1[(size_t)k*64 + t];
    h_s[t] = fmaxf(a, 0.f);
  }
  __syncthreads();
  if (t < 2){
    float a = bl2[t];
    for (int i=0;i<64;++i) a += h_s[i]*Wl2[(size_t)i*2 + t];
    out[(size_t)b*2 + t] = a;
  }
}

extern "C" void kernel_launch(void* const* d_in, const int* in_sizes, int n_in,
                              void* d_out, int out_size, void* d_ws, size_t ws_size,
                              hipStream_t stream){
  (void)in_sizes; (void)n_in; (void)out_size; (void)ws_size;
  const float* pos = (const float*)d_in[0];
  const float* W1  = (const float*)d_in[1];
  const float* b1  = (const float*)d_in[2];
  const float* W2  = (const float*)d_in[3];
  const float* b2  = (const float*)d_in[4];
  const float* W3  = (const float*)d_in[5];
  const float* b3  = (const float*)d_in[6];
  const float* Wl1 = (const float*)d_in[7];
  const float* bl1 = (const float*)d_in[8];
  const float* Wl2 = (const float*)d_in[9];
  const float* bl2 = (const float*)d_in[10];
  float* outp = (float*)d_out;

  char* w = (char*)d_ws;
  size_t off = 0;
  auto take = [&](size_t bytes)->char*{ char* p = w + off; off += (bytes + 255) & ~(size_t)255; return p; };
  float* sq    = (float*)take((size_t)BN*4);
  int*   idx   = (int*)  take((size_t)BN*NK*4);
  float* x1    = (float*)take((size_t)BN*64*4);
  float* x2    = (float*)take((size_t)BN*128*4);
  float* x3    = (float*)take((size_t)BN*256*4);
  float* stats = (float*)take(4096);
  float* spart = (float*)take((size_t)257*NSLOT*4);    // feature-major partials
  float* gpart = (float*)take((size_t)8*NB*256*4);
  float* wt2   = (float*)take((size_t)256*64*4);       // W2 pre-transposed [n][k]
  float* wt3   = (float*)take((size_t)512*128*4);      // W3 pre-transposed [n][k]
  float* big   = (float*)take((size_t)NBCH*NP*NP*4);   // dist chunk / xcat chunk (33.55 MB)
  float* dist  = big;
  float* xcat  = big;

  dim3 gdist(NP/128, NP/128, NBCH);

  // pre-transpose weights (tiny, once per call)
  k_wt<64,128><<<256, 64, 0, stream>>>(W2, wt2);
  k_wt<128,256><<<512, 128, 0, stream>>>(W3, wt3);

  // ---- layer 1 ----
  k_sq_pos<<<BN/256, 256, 0, stream>>>(pos, sq);
  for (int c=0;c<NB/NBCH;++c){
    k_dist2<<<gdist, 256, 0, stream>>>(pos, sq, dist, c*NBCH);
    k_topk<<<NBCH*NP/4, 256, 0, stream>>>(dist, idx, c*NBCH);
  }
  k_edge1<<<NSLOT, 256, 0, stream>>>(pos, idx, W1, b1, x1, spart);
  k_finalize2<64><<<1, 256, 0, stream>>>(spart, stats);
  k_norm<64><<<BN/4, 256, 0, stream>>>(x1, stats, sq);

  // ---- layer 2 ----
  for (int c=0;c<NB/NBCH;++c){
    k_tile<64,true><<<gdist, 256, 0, stream>>>(x1, x1, sq, dist, c*NBCH, NP);
    k_topk<<<NBCH*NP/4, 256, 0, stream>>>(dist, idx, c*NBCH);
  }
  k_tile<64,false><<<dim3(BN/128, 2), 256, 0, stream>>>(x1, wt2, nullptr, xcat, 0, 256);
  k_gmax<128><<<BN/32, 256, 0, stream>>>(xcat, idx, b2, x2, spart, 0, 0);
  k_finalize2<128><<<1, 256, 0, stream>>>(spart, stats);
  k_norm<128><<<BN/4, 256, 0, stream>>>(x2, stats, sq);

  // ---- layer 3 ----
  for (int c=0;c<NB/NBCH;++c){
    k_tile<128,true><<<gdist, 256, 0, stream>>>(x2, x2, sq, dist, c*NBCH, NP);
    k_topk<<<NBCH*NP/4, 256, 0, stream>>>(dist, idx, c*NBCH);
  }
  for (int h=0; h<2; ++h){
    int m_base = h * (BN/2);
    k_tile<128,false><<<dim3(BN/2/128, 4), 256, 0, stream>>>(x2, wt3, nullptr, xcat, m_base, 512);
    k_gmax<256><<<BN/2/32, 256, 0, stream>>>(xcat, idx, b3, x3, spart, m_base, h*(BN/2/32));
  }
  k_finalize2<256><<<1, 256, 0, stream>>>(spart, stats);
  k_norm<256><<<BN/4, 256, 0, stream>>>(x3, stats, sq);

  // ---- pool + head ----
  k_pool1<<<dim3(NB, 8), 256, 0, stream>>>(x3, gpart);
  k_head<<<NB, 256, 0, stream>>>(gpart, Wl1, bl1, Wl2, bl2, outp);
}

// Round 6
// 1769.382 us; speedup vs baseline: 1.5120x; 1.5120x over previous
//
#include <hip/hip_runtime.h>
#include <math.h>

constexpr int NB = 32;      // batches
constexpr int NP = 1024;    // points per batch
constexpr int NK = 10;      // k nearest (includes self)
constexpr int BN = NB * NP;
constexpr int NBCH = 8;     // batches per dist chunk
constexpr int NSLOT = 1024; // partial-reduction slots for PairNorm stats

__device__ __forceinline__ float4 ld4(const float* p){ return *reinterpret_cast<const float4*>(p); }
__device__ __forceinline__ float2 ld2(const float* p){ return *reinterpret_cast<const float2*>(p); }
__device__ __forceinline__ void st4(float* p, float4 v){ *reinterpret_cast<float4*>(p) = v; }

// async global->LDS, 16B per lane. LDS dest must be wave-uniform base + lane*16
// (our dests are lane-linear); swizzle is pre-applied to the GLOBAL source.
__device__ __forceinline__ void gload_lds16(const float* g, float4* l){
  __builtin_amdgcn_global_load_lds(
      (const __attribute__((address_space(1))) unsigned int*)g,
      (__attribute__((address_space(3))) unsigned int*)l,
      16, 0, 0);
}

// ---------------- sq norms of pos ----------------
__global__ __launch_bounds__(256) void k_sq_pos(const float* __restrict__ x, float* __restrict__ sq){
  int i = blockIdx.x*256 + threadIdx.x;
  float2 v = ld2(x + (size_t)2*i);
  sq[i] = v.x*v.x + v.y*v.y;
}

// ---------------- dist matrix, DIN=2 (layer 1) ----------------
__global__ __launch_bounds__(256) void k_dist2(const float* __restrict__ x,
    const float* __restrict__ sq, float* __restrict__ dist, int b0){
  int bz = blockIdx.z;
  int b = b0 + bz;
  int n0 = blockIdx.x*128, m0 = blockIdx.y*128;
  int ry = threadIdx.x>>4, rx = threadIdx.x&15;
  const float* xb = x + (size_t)b*NP*2;
  const float* sqb = sq + (size_t)b*NP;
  float2 av[8], bv[8]; float sn[8], sm[8];
#pragma unroll
  for (int k=0;k<8;++k){
    av[k] = ld2(xb + (size_t)(n0+ry*8+k)*2);
    bv[k] = ld2(xb + (size_t)(m0+rx*8+k)*2);
    sn[k] = sqb[n0+ry*8+k];
    sm[k] = sqb[m0+rx*8+k];
  }
  float* dbase = dist + ((size_t)bz*NP + n0 + ry*8)*NP + m0 + rx*8;
#pragma unroll
  for (int k=0;k<8;++k){
    float r[8];
#pragma unroll
    for (int l=0;l<8;++l){
      float dot = av[k].x*bv[l].x + av[k].y*bv[l].y;
      r[l] = (sn[k] + sm[l]) - 2.f*dot;
    }
    st4(dbase + (size_t)k*NP,     make_float4(r[0],r[1],r[2],r[3]));
    st4(dbase + (size_t)k*NP + 4, make_float4(r[4],r[5],r[6],r[7]));
  }
}

// ---------------- pre-transpose W into WT[n][k] (n in [0,2*DOUT)) ----------------
template<int DIN, int DOUT>
__global__ void k_wt(const float* __restrict__ W, float* __restrict__ WT){
  int n = blockIdx.x, k = threadIdx.x;
  float v = (n < DOUT) ? W[(size_t)k*DOUT + n]
                       : W[(size_t)DIN*DOUT + (size_t)k*DOUT + (n - DOUT)];
  WT[(size_t)n*DIN + k] = v;
}

// ---------------- unified 128x128 tile kernel (dist + gemm) ----------------
// BK=32 chunks, LDS double buffer (64KB -> 2 blocks/CU), staged via
// global_load_lds (no staging registers -> no spill; round-5 register
// prefetch hit the 256-VGPR cap and spilled ~1GB/dispatch).
// Pipeline per chunk: issue gl_lds(ch+1) -> vmcnt(8) -> s_barrier ->
// compute(ch) -> s_barrier. Counted vmcnt keeps prefetch in flight
// across the barrier (raw s_barrier avoids compiler's vmcnt(0) drain).
// LDS slot s holds (row r=s>>3, col c=((s&7)-(r>>3))&7) of the chunk
// => read (row,d4) at slot row*8 + ((d4+(row>>3))&7) (rotation swizzle,
// conflict-free a-side, 2-way b-side).
template<int DIN, bool DIST>
__global__ __launch_bounds__(256) void k_tile(const float* __restrict__ xa,
    const float* __restrict__ bsrc, const float* __restrict__ sq,
    float* __restrict__ out, int aux0, int outLD){
  constexpr int C = DIN/32;
  __shared__ float4 as4[2][1024];
  __shared__ float4 bs4[2][1024];
  int tid = threadIdx.x;
  const float* Arow; const float* Brow;
  float* obase; const float* sqn = nullptr; const float* sqm = nullptr;
  if constexpr (DIST){
    int bz = blockIdx.z; int b = aux0 + bz;
    int n0 = blockIdx.x*128, m0 = blockIdx.y*128;
    const float* xb = xa + (size_t)b*NP*DIN;
    Arow = xb + (size_t)n0*DIN;
    Brow = xb + (size_t)m0*DIN;
    sqn = sq + (size_t)b*NP + n0;
    sqm = sq + (size_t)b*NP + m0;
    obase = out + ((size_t)bz*NP + n0)*NP + m0;
  } else {
    int n0 = blockIdx.x*128, m0 = blockIdx.y*128;
    Arow = xa + (size_t)(aux0 + n0)*DIN;
    Brow = bsrc + (size_t)m0*DIN;
    obase = out + (size_t)n0*outLD + m0;
  }
  // per-thread pre-swizzled staging sources (chunk-invariant part)
  const float* pA[4]; const float* pB[4];
#pragma unroll
  for (int i=0;i<4;++i){
    int s = tid + 256*i;
    int r = s>>3;
    int c = ((s&7) - (r>>3)) & 7;
    pA[i] = Arow + (size_t)r*DIN + 4*c;
    pB[i] = Brow + (size_t)r*DIN + 4*c;
  }
  // prologue: chunk 0 -> buffer 0 (8 outstanding)
#pragma unroll
  for (int i=0;i<4;++i){
    gload_lds16(pA[i], &as4[0][tid+256*i]);
    gload_lds16(pB[i], &bs4[0][tid+256*i]);
  }
  int ry = tid>>4, rx = tid&15;
  float acc[8][8];
#pragma unroll
  for (int k=0;k<8;++k)
#pragma unroll
    for (int l=0;l<8;++l) acc[k][l] = 0.f;

#pragma unroll
  for (int ch=0; ch<C; ++ch){
    if (ch+1 < C){
      int nxt = (ch+1)&1;
#pragma unroll
      for (int i=0;i<4;++i){
        gload_lds16(pA[i] + (ch+1)*32, &as4[nxt][tid+256*i]);
        gload_lds16(pB[i] + (ch+1)*32, &bs4[nxt][tid+256*i]);
      }
      asm volatile("s_waitcnt vmcnt(8)" ::: "memory");   // chunk ch landed; ch+1 in flight
    } else {
      asm volatile("s_waitcnt vmcnt(0)" ::: "memory");
    }
    __builtin_amdgcn_sched_barrier(0);
    __builtin_amdgcn_s_barrier();
    int cur = ch&1;
#pragma unroll
    for (int d4=0; d4<8; ++d4){
      float4 a_[8], b_[8];
#pragma unroll
      for (int k=0;k<8;++k) a_[k] = as4[cur][(ry*8+k)*8 + ((d4 + ry)&7)];
#pragma unroll
      for (int l=0;l<8;++l) b_[l] = bs4[cur][(rx*8+l)*8 + ((d4 + rx)&7)];
#pragma unroll
      for (int k=0;k<8;++k)
#pragma unroll
        for (int l=0;l<8;++l)
          acc[k][l] += a_[k].x*b_[l].x + a_[k].y*b_[l].y + a_[k].z*b_[l].z + a_[k].w*b_[l].w;
    }
    __builtin_amdgcn_sched_barrier(0);
    __builtin_amdgcn_s_barrier();                        // buffer reuse fence
  }

  if constexpr (DIST){
    float sn[8], sm[8];
#pragma unroll
    for (int k=0;k<8;++k){ sn[k] = sqn[ry*8+k]; sm[k] = sqm[rx*8+k]; }
#pragma unroll
    for (int k=0;k<8;++k){
      float r[8];
#pragma unroll
      for (int l=0;l<8;++l) r[l] = (sn[k]+sm[l]) - 2.f*acc[k][l];
      float* op = obase + (size_t)(ry*8+k)*NP + rx*8;
      st4(op,     make_float4(r[0],r[1],r[2],r[3]));
      st4(op + 4, make_float4(r[4],r[5],r[6],r[7]));
    }
  } else {
#pragma unroll
    for (int k=0;k<8;++k){
      float* op = obase + (size_t)(ry*8+k)*outLD + rx*8;
      st4(op,     make_float4(acc[k][0],acc[k][1],acc[k][2],acc[k][3]));
      st4(op + 4, make_float4(acc[k][4],acc[k][5],acc[k][6],acc[k][7]));
    }
  }
}

// ---------------- gather-max epilogue: h = relu(z + b - y_self + max_j y_j) ----------------
template<int DOUT>
__global__ __launch_bounds__(256) void k_gmax(const float* __restrict__ xcat,
    const int* __restrict__ idx, const float* __restrict__ bias,
    float* __restrict__ hout, float* __restrict__ spart, int p_base, int slot_base){
  constexpr int TP = DOUT/4;        // threads per point
  constexpr int ROWS = 256/TP;      // points in flight
  constexpr int PPT = 32/ROWS;      // points per thread
  __shared__ int idx_s[32*NK];
  __shared__ float red[1024];       // ROWS*DOUT == 1024 floats
  __shared__ float ssp[4];
  int c4 = threadIdx.x % TP, pr = threadIdx.x / TP;
  int c = 4*c4;
  int p0 = blockIdx.x*32 + p_base;          // global first point of block
  for (int t=threadIdx.x; t<32*NK; t+=256) idx_s[t] = idx[(size_t)p0*NK + t];
  __syncthreads();
  float4 b4 = ld4(bias + c);
  float4 fsum = make_float4(0.f,0.f,0.f,0.f);
  float ss = 0.f;
  int pbl = (((p0 - p_base) >> 10) << 10);  // local batch base row
#pragma unroll
  for (int t=0; t<PPT; ++t){
    int pl = pr + t*ROWS;
    int lrow = (p0 - p_base) + pl;
    const float* row = xcat + (size_t)lrow*(2*DOUT);
    float4 z = ld4(row + c), ys = ld4(row + DOUT + c);
    float4 mv = make_float4(-__builtin_inff(),-__builtin_inff(),-__builtin_inff(),-__builtin_inff());
    for (int j=0;j<NK;++j){
      int q = pbl + idx_s[pl*NK + j];
      float4 g = ld4(xcat + (size_t)q*(2*DOUT) + DOUT + c);
      mv.x = fmaxf(mv.x, g.x); mv.y = fmaxf(mv.y, g.y);
      mv.z = fmaxf(mv.z, g.z); mv.w = fmaxf(mv.w, g.w);
    }
    float4 v;
    v.x = fmaxf(z.x + b4.x - ys.x + mv.x, 0.f);
    v.y = fmaxf(z.y + b4.y - ys.y + mv.y, 0.f);
    v.z = fmaxf(z.z + b4.z - ys.z + mv.z, 0.f);
    v.w = fmaxf(z.w + b4.w - ys.w + mv.w, 0.f);
    st4(hout + (size_t)(p0 + pl)*DOUT + c, v);
    fsum.x += v.x; fsum.y += v.y; fsum.z += v.z; fsum.w += v.w;
    ss += v.x*v.x + v.y*v.y + v.z*v.z + v.w*v.w;
  }
  st4(&red[pr*DOUT + c], fsum);
#pragma unroll
  for (int off=32; off; off>>=1) ss += __shfl_xor(ss, off, 64);
  if ((threadIdx.x&63)==0) ssp[threadIdx.x>>6] = ss;
  __syncthreads();
  int slot = slot_base + blockIdx.x;
  for (int o=threadIdx.x; o<DOUT; o+=256){
    float s = 0.f;
#pragma unroll
    for (int r=0;r<ROWS;++r) s += red[r*DOUT + o];
    spart[(size_t)o*NSLOT + slot] = s;
  }
  if (threadIdx.x==0) spart[(size_t)DOUT*NSLOT + slot] = ssp[0]+ssp[1]+ssp[2]+ssp[3];
}

// ---------------- top-k selection (wave per row) ----------------
__global__ __launch_bounds__(256) void k_topk(const float* __restrict__ dist,
    int* __restrict__ idx, int b0){
  int wave = threadIdx.x>>6, lane = threadIdx.x&63;
  int rowg = blockIdx.x*4 + wave;          // = bz*NP + n
  int bz = rowg >> 10, n = rowg & 1023;
  const float* dr = dist + (size_t)rowg * NP;
  float dv[16];
#pragma unroll
  for (int t=0;t<16;++t) dv[t] = dr[lane + 64*t];
  int* out = idx + ((size_t)(b0+bz)*NP + n)*NK;
  for (int kk=0; kk<NK; ++kk){
    float bvv = dv[0]; int bm = lane;
#pragma unroll
    for (int t=1;t<16;++t){
      int m = lane + 64*t;
      if (dv[t] < bvv){ bvv = dv[t]; bm = m; }   // ascending m, strict < => lowest idx on tie
    }
#pragma unroll
    for (int off=32; off; off>>=1){
      float ov = __shfl_xor(bvv, off, 64);
      int om = __shfl_xor(bm, off, 64);
      if (ov < bvv || (ov == bvv && om < bm)){ bvv = ov; bm = om; }
    }
    if (lane == 0) out[kk] = bm;
    int tsel = bm>>6, lsel = bm&63;
#pragma unroll
    for (int t=0;t<16;++t)
      if (t == tsel && lane == lsel) dv[t] = __builtin_inff();   // static indexing
  }
}

// ---------------- edge conv layer 1 (din=2, dout=64) ----------------
__global__ __launch_bounds__(256) void k_edge1(const float* __restrict__ x,
    const int* __restrict__ idx, const float* __restrict__ W,
    const float* __restrict__ bias, float* __restrict__ hout,
    float* __restrict__ spart){
  __shared__ int idx_s[32*NK];
  __shared__ float red[4][64];
  __shared__ float ssw[4];
  int lane = threadIdx.x & 63, wv = threadIdx.x >> 6;
  int p0 = blockIdx.x * 32;
  int b = p0 >> 10;
  int pl0 = p0 & 1023;
  const float* xb = x + ((size_t)b<<10)*2;
  for (int t=threadIdx.x; t<32*NK; t+=256) idx_s[t] = idx[(size_t)p0*NK + t];
  __syncthreads();
  float w0=W[lane], w1=W[64+lane], w2=W[128+lane], w3=W[192+lane];
  float bi = bias[lane];
  float fsum = 0.f, ss = 0.f;
#pragma unroll
  for (int t=0;t<8;++t){
    int pl = wv*8 + t;
    float2 xi = ld2(xb + (size_t)(pl0+pl)*2);
    float common = xi.x*w0 + xi.y*w1 + bi;
    float mv = -__builtin_inff();
    for (int j=0;j<NK;++j){
      float2 xj = ld2(xb + (size_t)idx_s[pl*NK+j]*2);
      mv = fmaxf(mv, (xj.x-xi.x)*w2 + (xj.y-xi.y)*w3);
    }
    float v = fmaxf(common + mv, 0.f);
    hout[(size_t)(p0+pl)*64 + lane] = v;
    fsum += v; ss += v*v;
  }
  red[wv][lane] = fsum;
#pragma unroll
  for (int off=32; off; off>>=1) ss += __shfl_xor(ss, off, 64);
  if (lane==0) ssw[wv] = ss;
  __syncthreads();
  if (threadIdx.x < 64){
    float s = red[0][lane]+red[1][lane]+red[2][lane]+red[3][lane];
    spart[(size_t)lane*NSLOT + blockIdx.x] = s;
  }
  if (threadIdx.x==0) spart[(size_t)64*NSLOT + blockIdx.x] = ssw[0]+ssw[1]+ssw[2]+ssw[3];
}

// ---------------- finalize PairNorm stats from partials ----------------
template<int DOUT>
__global__ __launch_bounds__(256) void k_finalize2(const float* __restrict__ spart,
    float* __restrict__ stats){
  __shared__ float part[4];
  __shared__ float ssh;
  float musq = 0.f;
  for (int f = threadIdx.x; f <= DOUT; f += 256){
    const float* row = spart + (size_t)f*NSLOT;
    float4 a = make_float4(0.f,0.f,0.f,0.f);
    for (int s=0; s<NSLOT; s+=4){
      float4 v = ld4(row + s);
      a.x += v.x; a.y += v.y; a.z += v.z; a.w += v.w;
    }
    float s = (a.x + a.y) + (a.z + a.w);
    if (f < DOUT){
      float m = s * (1.f/BN);
      stats[320+f] = m;
      musq += m*m;
    } else {
      ssh = s;
    }
  }
#pragma unroll
  for (int off=32; off; off>>=1) musq += __shfl_xor(musq, off, 64);
  if ((threadIdx.x&63)==0) part[threadIdx.x>>6] = musq;
  __syncthreads();
  if (threadIdx.x==0){
    float mu2 = part[0]+part[1]+part[2]+part[3];
    float msn = ssh*(1.f/BN) - mu2;
    stats[576] = 1.f / sqrtf(1e-5f + msn);
  }
}

// ---------------- normalize in place + next-layer sq (wave per row) ----------------
template<int DOUT>
__global__ __launch_bounds__(256) void k_norm(float* __restrict__ h,
    const float* __restrict__ stats, float* __restrict__ sq){
  int lane = threadIdx.x&63, wv = threadIdx.x>>6;
  int row = blockIdx.x*4 + wv;
  float inv = stats[576];
  const float* mu = stats + 320;
  float* hr = h + (size_t)row*DOUT;
  float s = 0.f;
  if constexpr (DOUT == 64){
    float v = (hr[lane] - mu[lane]) * inv;
    hr[lane] = v;
    s = v*v;
  } else if constexpr (DOUT == 128){
    float2 x2 = ld2(hr + 2*lane), m2 = ld2(mu + 2*lane);
    float a = (x2.x - m2.x)*inv, b = (x2.y - m2.y)*inv;
    *reinterpret_cast<float2*>(hr + 2*lane) = make_float2(a,b);
    s = a*a + b*b;
  } else {
    float4 x4 = ld4(hr + 4*lane), m4 = ld4(mu + 4*lane);
    float4 v;
    v.x = (x4.x-m4.x)*inv; v.y = (x4.y-m4.y)*inv;
    v.z = (x4.z-m4.z)*inv; v.w = (x4.w-m4.w)*inv;
    st4(hr + 4*lane, v);
    s = v.x*v.x + v.y*v.y + v.z*v.z + v.w*v.w;
  }
#pragma unroll
  for (int off=32; off; off>>=1) s += __shfl_xor(s, off, 64);
  if (lane==0) sq[row] = s;
}

// ---------------- global max pool (partial) ----------------
__global__ __launch_bounds__(256) void k_pool1(const float* __restrict__ h, float* __restrict__ gpart){
  int b = blockIdx.x, c = blockIdx.y, o = threadIdx.x;
  const float* hp = h + ((size_t)b*NP + c*128)*256 + o;
  float m = -__builtin_inff();
  for (int n=0;n<128;++n) m = fmaxf(m, hp[(size_t)n*256]);
  gpart[((size_t)c*NB + b)*256 + o] = m;
}

// ---------------- pool finish + MLP head ----------------
__global__ __launch_bounds__(256) void k_head(const float* __restrict__ gpart,
    const float* __restrict__ Wl1, const float* __restrict__ bl1,
    const float* __restrict__ Wl2, const float* __restrict__ bl2,
    float* __restrict__ out){
  __shared__ float g_s[256];
  __shared__ float h_s[64];
  int b = blockIdx.x, t = threadIdx.x;
  float m = -__builtin_inff();
  for (int c=0;c<8;++c) m = fmaxf(m, gpart[((size_t)c*NB + b)*256 + t]);
  g_s[t] = m;
  __syncthreads();
  if (t < 64){
    float a = bl1[t];
    for (int k=0;k<256;++k) a += g_s[k]*Wl1[(size_t)k*64 + t];
    h_s[t] = fmaxf(a, 0.f);
  }
  __syncthreads();
  if (t < 2){
    float a = bl2[t];
    for (int i=0;i<64;++i) a += h_s[i]*Wl2[(size_t)i*2 + t];
    out[(size_t)b*2 + t] = a;
  }
}

extern "C" void kernel_launch(void* const* d_in, const int* in_sizes, int n_in,
                              void* d_out, int out_size, void* d_ws, size_t ws_size,
                              hipStream_t stream){
  (void)in_sizes; (void)n_in; (void)out_size; (void)ws_size;
  const float* pos = (const float*)d_in[0];
  const float* W1  = (const float*)d_in[1];
  const float* b1  = (const float*)d_in[2];
  const float* W2  = (const float*)d_in[3];
  const float* b2  = (const float*)d_in[4];
  const float* W3  = (const float*)d_in[5];
  const float* b3  = (const float*)d_in[6];
  const float* Wl1 = (const float*)d_in[7];
  const float* bl1 = (const float*)d_in[8];
  const float* Wl2 = (const float*)d_in[9];
  const float* bl2 = (const float*)d_in[10];
  float* outp = (float*)d_out;

  char* w = (char*)d_ws;
  size_t off = 0;
  auto take = [&](size_t bytes)->char*{ char* p = w + off; off += (bytes + 255) & ~(size_t)255; return p; };
  float* sq    = (float*)take((size_t)BN*4);
  int*   idx   = (int*)  take((size_t)BN*NK*4);
  float* x1    = (float*)take((size_t)BN*64*4);
  float* x2    = (float*)take((size_t)BN*128*4);
  float* x3    = (float*)take((size_t)BN*256*4);
  float* stats = (float*)take(4096);
  float* spart = (float*)take((size_t)257*NSLOT*4);    // feature-major partials
  float* gpart = (float*)take((size_t)8*NB*256*4);
  float* wt2   = (float*)take((size_t)256*64*4);       // W2 pre-transposed [n][k]
  float* wt3   = (float*)take((size_t)512*128*4);      // W3 pre-transposed [n][k]
  float* big   = (float*)take((size_t)NBCH*NP*NP*4);   // dist chunk / xcat chunk (33.55 MB)
  float* dist  = big;
  float* xcat  = big;

  dim3 gdist(NP/128, NP/128, NBCH);

  // pre-transpose weights (tiny, once per call)
  k_wt<64,128><<<256, 64, 0, stream>>>(W2, wt2);
  k_wt<128,256><<<512, 128, 0, stream>>>(W3, wt3);

  // ---- layer 1 ----
  k_sq_pos<<<BN/256, 256, 0, stream>>>(pos, sq);
  for (int c=0;c<NB/NBCH;++c){
    k_dist2<<<gdist, 256, 0, stream>>>(pos, sq, dist, c*NBCH);
    k_topk<<<NBCH*NP/4, 256, 0, stream>>>(dist, idx, c*NBCH);
  }
  k_edge1<<<NSLOT, 256, 0, stream>>>(pos, idx, W1, b1, x1, spart);
  k_finalize2<64><<<1, 256, 0, stream>>>(spart, stats);
  k_norm<64><<<BN/4, 256, 0, stream>>>(x1, stats, sq);

  // ---- layer 2 ----
  for (int c=0;c<NB/NBCH;++c){
    k_tile<64,true><<<gdist, 256, 0, stream>>>(x1, x1, sq, dist, c*NBCH, NP);
    k_topk<<<NBCH*NP/4, 256, 0, stream>>>(dist, idx, c*NBCH);
  }
  k_tile<64,false><<<dim3(BN/128, 2), 256, 0, stream>>>(x1, wt2, nullptr, xcat, 0, 256);
  k_gmax<128><<<BN/32, 256, 0, stream>>>(xcat, idx, b2, x2, spart, 0, 0);
  k_finalize2<128><<<1, 256, 0, stream>>>(spart, stats);
  k_norm<128><<<BN/4, 256, 0, stream>>>(x2, stats, sq);

  // ---- layer 3 ----
  for (int c=0;c<NB/NBCH;++c){
    k_tile<128,true><<<gdist, 256, 0, stream>>>(x2, x2, sq, dist, c*NBCH, NP);
    k_topk<<<NBCH*NP/4, 256, 0, stream>>>(dist, idx, c*NBCH);
  }
  for (int h=0; h<2; ++h){
    int m_base = h * (BN/2);
    k_tile<128,false><<<dim3(BN/2/128, 4), 256, 0, stream>>>(x2, wt3, nullptr, xcat, m_base, 512);
    k_gmax<256><<<BN/2/32, 256, 0, stream>>>(xcat, idx, b3, x3, spart, m_base, h*(BN/2/32));
  }
  k_finalize2<256><<<1, 256, 0, stream>>>(spart, stats);
  k_norm<256><<<BN/4, 256, 0, stream>>>(x3, stats, sq);

  // ---- pool + head ----
  k_pool1<<<dim3(NB, 8), 256, 0, stream>>>(x3, gpart);
  k_head<<<NB, 256, 0, stream>>>(gpart, Wl1, bl1, Wl2, bl2, outp);
}